// Round 3
// baseline (122.305 us; speedup 1.0000x reference)
//
#include <hip/hip_runtime.h>
#include <hip/hip_bf16.h>
#include <cstdint>

#define SEQ   1024
#define DOUT  1024
#define KDIM  1024
#define MTOT  4096      // BS*SEQ

typedef __bf16 bf16x8 __attribute__((ext_vector_type(8)));
typedef float  f32x4  __attribute__((ext_vector_type(4)));
typedef unsigned short ushort8v __attribute__((ext_vector_type(8)));

__device__ inline unsigned short f2bf(float f) {
  union { float f; unsigned u; } a; a.f = f;
  unsigned r = a.u + 0x7fff + ((a.u >> 16) & 1);   // RNE
  return (unsigned short)(r >> 16);
}

__device__ inline void gl16(const void* g, void* l) {
  __builtin_amdgcn_global_load_lds((__attribute__((address_space(1))) void*)g,
                                   (__attribute__((address_space(3))) void*)l, 16, 0, 0);
}

__device__ inline void barf() {
  asm volatile("" ::: "memory");
  __builtin_amdgcn_s_barrier();
  asm volatile("" ::: "memory");
}

// Launch 1 (fused front): blocks [0,256) self-contained thin GEMM (A in regs
// from f32 x, B panel built from phi/la in-register -> LDS once, 1 barrier,
// then pure ds_read+MFMA); [256,4352) x->xb; [4352,8448) W->Wc; [8448,8576)
// B2T; 8576 thr. k_prep is gone (one fewer node in the serial chain).
__global__ __launch_bounds__(256) void k_front(const float* __restrict__ x,
                                               const float4* __restrict__ x4, ushort4* __restrict__ xb4,
                                               const float* __restrict__ phi, const float* __restrict__ la,
                                               const float* __restrict__ lb, const float* __restrict__ W,
                                               const int* __restrict__ inst,
                                               unsigned short* __restrict__ Wc, unsigned short* __restrict__ B2T,
                                               int* __restrict__ thr, float* __restrict__ mwzP) {
  __shared__ __align__(16) unsigned short Bs8[8 * 48 * 32];   // 24 KB: [s][48][32] swizzled
  int blk = blockIdx.x, t = threadIdx.x;
  if (blk >= 256) {
    if (blk < 4352) {
      size_t i = (size_t)(blk - 256) * 256 + t;   // 1M float4 of x
      float4 v = x4[i];
      ushort4 o; o.x = f2bf(v.x); o.y = f2bf(v.y); o.z = f2bf(v.z); o.w = f2bf(v.w);
      xb4[i] = o;
    } else if (blk < 8448) {
      size_t i = (size_t)(blk - 4352) * 256 + t;  // 1M elems of W
      Wc[i] = f2bf(W[i]);
    } else if (blk < 8576) {
      int i = (blk - 8448) * 256 + t;             // 32768: B2T[n][kr] = lb[kr][n]
      int n = i >> 5, kr = i & 31;
      B2T[i] = f2bf(lb[kr * 1024 + n]);
    } else {
      int b = t >> 6, lane = t & 63;              // wave b handles batch b
      int fo = 1 << 30, no = 0;
#pragma unroll
      for (int j = 0; j < 16; ++j) {
        int p = j * 64 + lane;
        int iv = inst[b * SEQ + p];
        if (iv > 0) fo = min(fo, p);
        no += iv;
      }
#pragma unroll
      for (int d = 1; d < 64; d <<= 1) { fo = min(fo, __shfl_xor(fo, d)); no += __shfl_xor(no, d); }
      if (lane == 0) thr[b] = (no > 0) ? fo + no : 0;
    }
    return;
  }
  // ---- thin GEMM: out-rows bm*64..+64, K-slice ks*256..+256, 40 cols ----
  int bm = blk & 63, ks = blk >> 6;
  int wave = t >> 6, lane = t & 63;
  int quad = lane >> 4, lr = lane & 15;
  // A fragments straight to registers: row bm*64+wave*16+lr, cols ks*256+s*32+quad*8
  bf16x8 af[8];
  {
    const float* aP = x + (size_t)(bm * 64 + wave * 16 + lr) * KDIM + ks * 256 + quad * 8;
#pragma unroll
    for (int s = 0; s < 8; ++s) {
      float4 u0 = *(const float4*)(aP + s * 32);
      float4 u1 = *(const float4*)(aP + s * 32 + 4);
      bf16x8 v;
      v[0] = (__bf16)u0.x; v[1] = (__bf16)u0.y; v[2] = (__bf16)u0.z; v[3] = (__bf16)u0.w;
      v[4] = (__bf16)u1.x; v[5] = (__bf16)u1.y; v[6] = (__bf16)u1.z; v[7] = (__bf16)u1.w;
      af[s] = v;
    }
  }
  // B panel [48][256] built from phi/la, staged once. Row rb: rb<8 -> phi col rb;
  // rb<40 -> la (k=kr>>2, r=kr&3); else zero. XOR-swizzle chunk: c ^ ((rb&3)*8).
  if (t < 192) {
    int rb = t >> 2, c0 = (t & 3) * 8;
    int sw = (rb & 3) * 8;
    const float4* la4 = (const float4*)la;
#pragma unroll
    for (int s = 0; s < 8; ++s) {
      ushort8v u;
      if (rb < 8) {
#pragma unroll
        for (int j = 0; j < 8; ++j) {
          int d = ks * 256 + s * 32 + c0 + j;
          u[j] = f2bf(phi[d * 8 + rb]);
        }
      } else if (rb < 40) {
        int kr = rb - 8;
#pragma unroll
        for (int j = 0; j < 8; ++j) {
          int d = ks * 256 + s * 32 + c0 + j;
          float4 v = la4[(size_t)(kr >> 2) * 1024 + d];
          float vv = (kr & 3) == 0 ? v.x : (kr & 3) == 1 ? v.y : (kr & 3) == 2 ? v.z : v.w;
          u[j] = f2bf(vv);
        }
      } else {
#pragma unroll
        for (int j = 0; j < 8; ++j) u[j] = 0;
      }
      *reinterpret_cast<__shared__ ushort8v*>(&Bs8[s * 1536 + rb * 32 + (c0 ^ sw)]) = u;
    }
  }
  __syncthreads();
  f32x4 acc[3];
#pragma unroll
  for (int i = 0; i < 3; ++i) acc[i] = (f32x4){0.f, 0.f, 0.f, 0.f};
#pragma unroll
  for (int s = 0; s < 8; ++s) {
#pragma unroll
    for (int ni = 0; ni < 3; ++ni) {
      int rB = ni * 16 + lr;
      bf16x8 bfr = *(const bf16x8*)&Bs8[s * 1536 + rB * 32 + ((quad * 8) ^ ((rB & 3) * 8))];
      acc[ni] = __builtin_amdgcn_mfma_f32_16x16x32_bf16(af[s], bfr, acc[ni], 0, 0, 0);
    }
  }
#pragma unroll
  for (int ni = 0; ni < 3; ++ni) {
    int c = ni * 16 + lr;
#pragma unroll
    for (int rg = 0; rg < 4; ++rg) {
      int row = bm * 64 + wave * 16 + quad * 4 + rg;
      if (c < 40) mwzP[(size_t)(ks * 40 + c) * MTOT + row] = acc[ni][rg];
    }
  }
}

// Launch 2 (unchanged): fused scan+gate, block (b,c)
__global__ __launch_bounds__(1024) void k_scan_gate(const float* __restrict__ mwzP,
                                                    const int* __restrict__ pad, const int* __restrict__ thr,
                                                    unsigned short* __restrict__ gb) {
  int b = blockIdx.x, c = blockIdx.y;
  int tid = threadIdx.x, wv = tid >> 6, lane = tid & 63;
  __shared__ float wsz[16], wsp[16];
  __shared__ float sv, spc;
  int q = b * SEQ + tid;
  float pm = (float)pad[q];
  float z = 0.f;
#pragma unroll
  for (int s = 0; s < 4; ++s) z += mwzP[(size_t)(s * 40 + 8 + c) * MTOT + q];
  z *= pm;
  float vz = z, vp = pm;
#pragma unroll
  for (int d = 1; d < 64; d <<= 1) {
    float oz = __shfl_up(vz, d), op = __shfl_up(vp, d);
    if (lane >= d) { vz += oz; vp += op; }
  }
  if (lane == 63) { wsz[wv] = vz; wsp[wv] = vp; }
  __syncthreads();
  if (wv == 0 && lane < 16) {
    float oz = wsz[lane], op = wsp[lane], sz = oz, sp = op;
#pragma unroll
    for (int d = 1; d < 16; d <<= 1) {
      float tz = __shfl_up(sz, d), tp = __shfl_up(sp, d);
      if (lane >= d) { sz += tz; sp += tp; }
    }
    wsz[lane] = sz - oz; wsp[lane] = sp - op;   // exclusive wave offsets
  }
  __syncthreads();
  vz += wsz[wv]; vp += wsp[wv];
  int th = thr[b];
  if (th > 0 && tid == th - 1) { sv = vz; spc = vp; }
  __syncthreads();
  unsigned short o = 0;
  if (pm != 0.f) {
    bool own = (tid + 1 >= th);
    float Tv  = own ? vz : sv;
    float cnt = own ? vp : spc;
    float C[8], mx = -1e30f;
#pragma unroll
    for (int k = 0; k < 8; ++k) {
      float m = 0.f;
#pragma unroll
      for (int s = 0; s < 4; ++s) m += mwzP[(size_t)(s * 40 + k) * MTOT + q];
      C[k] = m; mx = fmaxf(mx, m);
    }
    float sm = 0.f;
#pragma unroll
    for (int k = 0; k < 8; ++k) { C[k] = __expf(C[k] - mx); sm += C[k]; }
    o = f2bf(C[c >> 2] * Tv / (sm * cnt));
  }
  gb[(size_t)q * 32 + c] = o;
}

// Launch 3: BM=128 x BN=64, BK=64, 128 threads / 2 waves, wave tile 64x64
// (4x4 acc) -> ds_read/MFMA ratio 0.5 vs 0.75. Double-buffered LDS, counted
// vmcnt(12) so next tile's 12 gl16/thread stay in flight across compute.
// XOR-swizzle (source-side + read-side).
__global__ __launch_bounds__(128) void k_gemm(const unsigned short* __restrict__ A,
                                              const unsigned short* __restrict__ Wc,
                                              const unsigned short* __restrict__ gb,
                                              const unsigned short* __restrict__ B2T,
                                              float* __restrict__ out,
                                              const float* __restrict__ bias) {
  __shared__ __align__(16) unsigned short As[2][128 * 64];  // 16 KB x2
  __shared__ __align__(16) unsigned short Bs[2][64 * 64];   // 8 KB x2
  int bm = blockIdx.x, bn = blockIdx.y;
  int t = threadIdx.x;
  int wave = t >> 6, lane = t & 63;        // wave tile: rows wave*64..+64, all 64 cols
  int quad = lane >> 4, lr = lane & 15;
  f32x4 acc[4][4];
#pragma unroll
  for (int i = 0; i < 4; i++)
#pragma unroll
    for (int j = 0; j < 4; j++) acc[i][j] = (f32x4){0.f, 0.f, 0.f, 0.f};

  // adapter prologue: acc += g-tile @ B2 (register fragments only)
  {
    bf16x8 ga[4], gBf[4];
#pragma unroll
    for (int mi = 0; mi < 4; mi++)
      ga[mi] = *(const bf16x8*)(gb + (size_t)(bm * 128 + wave * 64 + mi * 16 + lr) * 32 + quad * 8);
#pragma unroll
    for (int ni = 0; ni < 4; ni++)
      gBf[ni] = *(const bf16x8*)(B2T + (size_t)(bn * 64 + ni * 16 + lr) * 32 + quad * 8);
#pragma unroll
    for (int mi = 0; mi < 4; mi++)
#pragma unroll
      for (int ni = 0; ni < 4; ni++)
        acc[mi][ni] = __builtin_amdgcn_mfma_f32_16x16x32_bf16(ga[mi], gBf[ni], acc[mi][ni], 0, 0, 0);
  }

  const unsigned short* aG = A + (size_t)bm * 128 * KDIM;
  const unsigned short* bG = Wc + (size_t)bn * 64 * KDIM;

  // stage one BK=64 tile into buffer b (12 gl16/thread at 128 thr).
  // LDS linear in chunk order; source column pre-XOR'd: LDS[r][u] = G[r][u^(r&7)*8].
  auto stage = [&](int b, int kb) {
#pragma unroll
    for (int i = 0; i < 8; ++i) {                 // A: 128x64 = 1024 chunks
      int g = i * 128 + t;
      int r = g >> 3, c = (g & 7) * 8;
      int cs = c ^ ((r & 7) * 8);
      gl16(aG + (size_t)r * KDIM + kb + cs, &As[b][i * 1024 + wave * 512]);
    }
#pragma unroll
    for (int i = 0; i < 4; ++i) {                 // B: 64x64 = 512 chunks
      int g = i * 128 + t;
      int r = g >> 3, c = (g & 7) * 8;
      int cs = c ^ ((r & 7) * 8);
      gl16(bG + (size_t)r * KDIM + kb + cs, &Bs[b][i * 1024 + wave * 512]);
    }
  };

  stage(0, 0);
  asm volatile("s_waitcnt vmcnt(0)" ::: "memory");
  barf();
  for (int it = 0; it < 16; ++it) {
    int cur = it & 1;
    if (it < 15) {
      stage(cur ^ 1, (it + 1) * 64);              // 12 loads stay in flight across barriers
      asm volatile("s_waitcnt vmcnt(12)" ::: "memory");  // wait only for tile `cur`
    } else {
      asm volatile("s_waitcnt vmcnt(0)" ::: "memory");
    }
    barf();                                       // every wave's `cur` writes landed
#pragma unroll
    for (int kk = 0; kk < 2; ++kk) {
      bf16x8 af[4], bfr[4];
#pragma unroll
      for (int mi = 0; mi < 4; mi++) {
        int R = wave * 64 + mi * 16 + lr;
        int cc = (kk * 32 + quad * 8) ^ ((R & 7) * 8);
        af[mi] = *(const bf16x8*)&As[cur][R * 64 + cc];
      }
#pragma unroll
      for (int ni = 0; ni < 4; ni++) {
        int R = ni * 16 + lr;
        int cc = (kk * 32 + quad * 8) ^ ((R & 7) * 8);
        bfr[ni] = *(const bf16x8*)&Bs[cur][R * 64 + cc];
      }
#pragma unroll
      for (int mi = 0; mi < 4; mi++)
#pragma unroll
        for (int ni = 0; ni < 4; ni++)
          acc[mi][ni] = __builtin_amdgcn_mfma_f32_16x16x32_bf16(af[mi], bfr[ni], acc[mi][ni], 0, 0, 0);
    }
    barf();                                       // all waves done reading buf `cur`
  }

  // epilogue: C/D layout col=lane&15, row=quad*4+reg
#pragma unroll
  for (int mi = 0; mi < 4; mi++) {
#pragma unroll
    for (int ni = 0; ni < 4; ni++) {
      int col = bn * 64 + ni * 16 + lr;
      float bv = bias[col];
#pragma unroll
      for (int rg = 0; rg < 4; ++rg) {
        int row = bm * 128 + wave * 64 + mi * 16 + quad * 4 + rg;
        out[(size_t)row * DOUT + col] = acc[mi][ni][rg] + bv;
      }
    }
  }
}

extern "C" void kernel_launch(void* const* d_in, const int* in_sizes, int n_in,
                              void* d_out, int out_size, void* d_ws, size_t ws_size,
                              hipStream_t stream) {
  const float* x    = (const float*)d_in[0];
  const float* phi  = (const float*)d_in[1];
  const float* la   = (const float*)d_in[2];
  const float* lb   = (const float*)d_in[3];
  const float* W    = (const float*)d_in[4];
  const float* bias = (const float*)d_in[5];
  const int*   inst = (const int*)d_in[6];
  const int*   pad  = (const int*)d_in[7];
  float* out = (float*)d_out;

  char* ws = (char*)d_ws;
  unsigned short* xb  = (unsigned short*)ws;                   // 8388608 B
  unsigned short* Wc  = (unsigned short*)(ws + 8388608);       // 2097152 B (rows 0..1023 only now)
  unsigned short* B2T = (unsigned short*)(ws + 10584064);      // [1024][32] bf16 = 65536 B
  float* mwzP = (float*)(ws + 10649600);                       // [4][40][4096] f32 = 2621440 B
  unsigned short* gb  = (unsigned short*)(ws + 13271040);      // [4096][32] bf16 = 262144 B
  int*   thr  = (int*)(ws + 13533184);                         // 16 B

  hipLaunchKernelGGL(k_front,     dim3(8577),   dim3(256),  0, stream,
                     x, (const float4*)x, (ushort4*)xb, phi, la, lb, W, inst,
                     Wc, B2T, thr, mwzP);
  hipLaunchKernelGGL(k_scan_gate, dim3(4, 32),  dim3(1024), 0, stream, mwzP, pad, thr, gb);
  hipLaunchKernelGGL(k_gemm,      dim3(32, 16), dim3(128),  0, stream, xb, Wc, gb, B2T, out, bias);
}

// Round 5
// 110.161 us; speedup vs baseline: 1.1102x; 1.1102x over previous
//
#include <hip/hip_runtime.h>
#include <hip/hip_bf16.h>
#include <cstdint>

#define SEQ   1024
#define DOUT  1024
#define KDIM  1024
#define MTOT  4096      // BS*SEQ

typedef __bf16 bf16x8 __attribute__((ext_vector_type(8)));
typedef float  f32x4  __attribute__((ext_vector_type(4)));
typedef unsigned short ushort8v __attribute__((ext_vector_type(8)));

__device__ inline unsigned short f2bf(float f) {
  union { float f; unsigned u; } a; a.f = f;
  unsigned r = a.u + 0x7fff + ((a.u >> 16) & 1);   // RNE
  return (unsigned short)(r >> 16);
}

__device__ inline void gl16(const void* g, void* l) {
  __builtin_amdgcn_global_load_lds((__attribute__((address_space(1))) void*)g,
                                   (__attribute__((address_space(3))) void*)l, 16, 0, 0);
}

__device__ inline void barf() {
  asm volatile("" ::: "memory");
  __builtin_amdgcn_s_barrier();
  asm volatile("" ::: "memory");
}

// Launch 1 (R2-proven): tiny independent prep — Wc rows 1024..1072
// (phi^T, A2^T, zero pad) for the thin GEMM's B panel, B2T, thr. 321 blocks.
__global__ __launch_bounds__(256) void k_prep(const float* __restrict__ phi, const float* __restrict__ la,
                                              const float* __restrict__ lb, const int* __restrict__ inst,
                                              unsigned short* __restrict__ Wc, unsigned short* __restrict__ B2T,
                                              int* __restrict__ thr) {
  int blk = blockIdx.x, tid = threadIdx.x;
  if (blk < 192) {
    int i = blk * 256 + tid;                     // 48 rows x 1024 exact
    int row = 1024 + (i >> 10), d = i & 1023;
    float v;
    if (row < 1032)       v = phi[d * 8 + (row - 1024)];
    else if (row < 1064)  { int kr = row - 1032; v = la[(kr >> 2) * 4096 + d * 4 + (kr & 3)]; }
    else                  v = 0.f;
    Wc[(size_t)row * 1024 + d] = f2bf(v);
  } else if (blk < 320) {
    int i = (blk - 192) * 256 + tid;             // 32768: B2T[n][kr] = lb[kr][n]
    int n = i >> 5, kr = i & 31;
    B2T[i] = f2bf(lb[kr * 1024 + n]);
  } else {
    int b = tid >> 6, lane = tid & 63;           // wave b handles batch b
    int fo = 1 << 30, no = 0;
#pragma unroll
    for (int j = 0; j < 16; ++j) {
      int p = j * 64 + lane;
      int iv = inst[b * SEQ + p];
      if (iv > 0) fo = min(fo, p);
      no += iv;
    }
#pragma unroll
    for (int d = 1; d < 64; d <<= 1) { fo = min(fo, __shfl_xor(fo, d)); no += __shfl_xor(no, d); }
    if (lane == 0) thr[b] = (no > 0) ? fo + no : 0;
  }
}

// Launch 2 (R2-proven): blocks [0,256) = thin GEMM (A from f32 x, reg-staged +
// converted, one-step register prefetch + counted-vmcnt barrier); [256,4352)
// x->xb bf16; [4352,8448) W->Wc bf16. Memory blocks fill idle wave slots.
__global__ __launch_bounds__(256) void k_mwz(const float* __restrict__ x,
                                             const float4* __restrict__ x4, ushort4* __restrict__ xb4,
                                             const unsigned short* __restrict__ Wc0,
                                             const float* __restrict__ W,
                                             unsigned short* __restrict__ Wc,
                                             float* __restrict__ mwzP) {
  __shared__ __align__(16) unsigned short As[64 * 32];
  __shared__ __align__(16) unsigned short Bs[48 * 32];
  int blk = blockIdx.x, t = threadIdx.x;
  if (blk >= 256) {
    if (blk < 4352) {
      size_t i = (size_t)(blk - 256) * 256 + t;   // 1M float4 of x
      float4 v = x4[i];
      ushort4 o; o.x = f2bf(v.x); o.y = f2bf(v.y); o.z = f2bf(v.z); o.w = f2bf(v.w);
      xb4[i] = o;
    } else {
      size_t i = (size_t)(blk - 4352) * 256 + t;  // 1M elems of W
      Wc[i] = f2bf(W[i]);
    }
    return;
  }
  int bm = blk & 63, ks = blk >> 6;
  int wave = t >> 6, lane = t & 63;
  int quad = lane >> 4, lr = lane & 15;
  f32x4 acc[3];
#pragma unroll
  for (int i = 0; i < 3; ++i) acc[i] = (f32x4){0.f, 0.f, 0.f, 0.f};
  const float* aF = x + (size_t)(bm * 64) * KDIM + ks * 256;
  const unsigned short* bG = Wc0 + (size_t)1024 * KDIM + ks * 256;
  int r0 = t >> 2, c0 = (t & 3) * 8;
  const float* aP = aF + (size_t)r0 * KDIM + c0;
  float4 a0 = *(const float4*)(aP);
  float4 a1 = *(const float4*)(aP + 4);
  for (int kb = 0; kb < 256; kb += 32) {
    barf();                                       // all waves done reading As/Bs
    ushort8v u;
    u[0] = f2bf(a0.x); u[1] = f2bf(a0.y); u[2] = f2bf(a0.z); u[3] = f2bf(a0.w);
    u[4] = f2bf(a1.x); u[5] = f2bf(a1.y); u[6] = f2bf(a1.z); u[7] = f2bf(a1.w);
    *reinterpret_cast<__shared__ ushort8v*>(&As[t * 8]) = u;   // byte t*16, same layout as gl16 wrote
    if (t < 192) gl16(bG + (size_t)r0 * KDIM + kb + c0, &Bs[wave * 512]);
    if (kb + 32 < 256) {                          // prefetch next A slice (stays in flight)
      asm volatile("" ::: "memory");              // keep issue order: gl16 first, then these
      a0 = *(const float4*)(aP + kb + 32);
      a1 = *(const float4*)(aP + kb + 36);
      asm volatile("s_waitcnt vmcnt(2) lgkmcnt(0)" ::: "memory");  // B staged, ds_write visible; A still in flight
    } else {
      asm volatile("s_waitcnt vmcnt(0) lgkmcnt(0)" ::: "memory");
    }
    barf();                                       // stage complete for all waves
    bf16x8 af = *(const bf16x8*)&As[(wave * 16 + lr) * 32 + quad * 8];
#pragma unroll
    for (int ni = 0; ni < 3; ++ni) {
      bf16x8 bfr = *(const bf16x8*)&Bs[(ni * 16 + lr) * 32 + quad * 8];
      acc[ni] = __builtin_amdgcn_mfma_f32_16x16x32_bf16(af, bfr, acc[ni], 0, 0, 0);
    }
  }
#pragma unroll
  for (int ni = 0; ni < 3; ++ni) {
    int c = ni * 16 + lr;
#pragma unroll
    for (int rg = 0; rg < 4; ++rg) {
      int row = bm * 64 + wave * 16 + quad * 4 + rg;
      if (c < 40) mwzP[(size_t)(ks * 40 + c) * MTOT + row] = acc[ni][rg];
    }
  }
}

// Launch 3 (R2-proven, unchanged): fused scan+gate, block (b,c)
__global__ __launch_bounds__(1024) void k_scan_gate(const float* __restrict__ mwzP,
                                                    const int* __restrict__ pad, const int* __restrict__ thr,
                                                    unsigned short* __restrict__ gb) {
  int b = blockIdx.x, c = blockIdx.y;
  int tid = threadIdx.x, wv = tid >> 6, lane = tid & 63;
  __shared__ float wsz[16], wsp[16];
  __shared__ float sv, spc;
  int q = b * SEQ + tid;
  float pm = (float)pad[q];
  float z = 0.f;
#pragma unroll
  for (int s = 0; s < 4; ++s) z += mwzP[(size_t)(s * 40 + 8 + c) * MTOT + q];
  z *= pm;
  float vz = z, vp = pm;
#pragma unroll
  for (int d = 1; d < 64; d <<= 1) {
    float oz = __shfl_up(vz, d), op = __shfl_up(vp, d);
    if (lane >= d) { vz += oz; vp += op; }
  }
  if (lane == 63) { wsz[wv] = vz; wsp[wv] = vp; }
  __syncthreads();
  if (wv == 0 && lane < 16) {
    float oz = wsz[lane], op = wsp[lane], sz = oz, sp = op;
#pragma unroll
    for (int d = 1; d < 16; d <<= 1) {
      float tz = __shfl_up(sz, d), tp = __shfl_up(sp, d);
      if (lane >= d) { sz += tz; sp += tp; }
    }
    wsz[lane] = sz - oz; wsp[lane] = sp - op;   // exclusive wave offsets
  }
  __syncthreads();
  vz += wsz[wv]; vp += wsp[wv];
  int th = thr[b];
  if (th > 0 && tid == th - 1) { sv = vz; spc = vp; }
  __syncthreads();
  unsigned short o = 0;
  if (pm != 0.f) {
    bool own = (tid + 1 >= th);
    float Tv  = own ? vz : sv;
    float cnt = own ? vp : spc;
    float C[8], mx = -1e30f;
#pragma unroll
    for (int k = 0; k < 8; ++k) {
      float m = 0.f;
#pragma unroll
      for (int s = 0; s < 4; ++s) m += mwzP[(size_t)(s * 40 + k) * MTOT + q];
      C[k] = m; mx = fmaxf(mx, m);
    }
    float sm = 0.f;
#pragma unroll
    for (int k = 0; k < 8; ++k) { C[k] = __expf(C[k] - mx); sm += C[k]; }
    o = f2bf(C[c >> 2] * Tv / (sm * cnt));
  }
  gb[(size_t)q * 32 + c] = o;
}

// Launch 4 (R2 body + ONE change: XCD-aware bijective (bm,bn) remap, T1).
// Each XCD owns an 8x8 tile region -> working set 8 A-panels (2MB) + 8
// B-panels (1MB) = 3MB < 4MB per-XCD L2, so panel re-reads become L2 hits.
// BM=128 x BN=64, BK=64, double-buffered LDS, counted vmcnt(6), XOR-swizzle.
__global__ __launch_bounds__(256) void k_gemm(const unsigned short* __restrict__ A,
                                              const unsigned short* __restrict__ Wc,
                                              const unsigned short* __restrict__ gb,
                                              const unsigned short* __restrict__ B2T,
                                              float* __restrict__ out,
                                              const float* __restrict__ bias) {
  __shared__ __align__(16) unsigned short As[2][128 * 64];  // 16 KB x2
  __shared__ __align__(16) unsigned short Bs[2][64 * 64];   // 8 KB x2
  // XCD remap: blocks dispatched round-robin over 8 XCDs (blk%8 = XCD id).
  // Give XCD x the 8x8 region bm in [(x&3)*8,+8), bn in [(x>>2)*8,+8).
  int blk = blockIdx.x;
  int xcd = blk & 7, idx = blk >> 3;
  int bm = (xcd & 3) * 8 + (idx & 7);
  int bn = (xcd >> 2) * 8 + (idx >> 3);
  int t = threadIdx.x;
  int wave = t >> 6, lane = t & 63;
  int wr = wave >> 1, wc = wave & 1;       // wave: 64 rows x 32 cols
  int quad = lane >> 4, lr = lane & 15;
  f32x4 acc[4][2];
#pragma unroll
  for (int i = 0; i < 4; i++)
#pragma unroll
    for (int j = 0; j < 2; j++) acc[i][j] = (f32x4){0.f, 0.f, 0.f, 0.f};

  // adapter prologue: acc += g-tile @ B2 (register fragments only)
  {
    bf16x8 ga[4], gBf[2];
#pragma unroll
    for (int mi = 0; mi < 4; mi++)
      ga[mi] = *(const bf16x8*)(gb + (size_t)(bm * 128 + wr * 64 + mi * 16 + lr) * 32 + quad * 8);
#pragma unroll
    for (int ni = 0; ni < 2; ni++)
      gBf[ni] = *(const bf16x8*)(B2T + (size_t)(bn * 64 + wc * 32 + ni * 16 + lr) * 32 + quad * 8);
#pragma unroll
    for (int mi = 0; mi < 4; mi++)
#pragma unroll
      for (int ni = 0; ni < 2; ni++)
        acc[mi][ni] = __builtin_amdgcn_mfma_f32_16x16x32_bf16(ga[mi], gBf[ni], acc[mi][ni], 0, 0, 0);
  }

  const unsigned short* aG = A + (size_t)bm * 128 * KDIM;
  const unsigned short* bG = Wc + (size_t)bn * 64 * KDIM;

  // stage one BK=64 tile into buffer b (6 gl16/thread). LDS linear in chunk
  // order; source column pre-XOR'd: LDS[r][u] = G[r][u^(r&7)*8].
  auto stage = [&](int b, int kb) {
#pragma unroll
    for (int i = 0; i < 4; ++i) {                 // A: 128x64 = 1024 chunks
      int g = i * 256 + t;
      int r = g >> 3, c = (g & 7) * 8;
      int cs = c ^ ((r & 7) * 8);
      gl16(aG + (size_t)r * KDIM + kb + cs, &As[b][i * 2048 + wave * 512]);
    }
#pragma unroll
    for (int i = 0; i < 2; ++i) {                 // B: 64x64 = 512 chunks
      int g = i * 256 + t;
      int r = g >> 3, c = (g & 7) * 8;
      int cs = c ^ ((r & 7) * 8);
      gl16(bG + (size_t)r * KDIM + kb + cs, &Bs[b][i * 2048 + wave * 512]);
    }
  };

  stage(0, 0);
  asm volatile("s_waitcnt vmcnt(0)" ::: "memory");
  barf();
  for (int it = 0; it < 16; ++it) {
    int cur = it & 1;
    if (it < 15) {
      stage(cur ^ 1, (it + 1) * 64);              // 6 loads stay in flight across barriers
      asm volatile("s_waitcnt vmcnt(6)" ::: "memory");   // wait only for tile `cur` (issued last iter)
    } else {
      asm volatile("s_waitcnt vmcnt(0)" ::: "memory");
    }
    barf();                                       // every wave's `cur` writes landed
#pragma unroll
    for (int kk = 0; kk < 2; ++kk) {
      bf16x8 af[4], bfr[2];
#pragma unroll
      for (int mi = 0; mi < 4; mi++) {
        int R = wr * 64 + mi * 16 + lr;
        int cc = (kk * 32 + quad * 8) ^ ((R & 7) * 8);
        af[mi] = *(const bf16x8*)&As[cur][R * 64 + cc];
      }
#pragma unroll
      for (int ni = 0; ni < 2; ni++) {
        int R = wc * 32 + ni * 16 + lr;
        int cc = (kk * 32 + quad * 8) ^ ((R & 7) * 8);
        bfr[ni] = *(const bf16x8*)&Bs[cur][R * 64 + cc];
      }
#pragma unroll
      for (int mi = 0; mi < 4; mi++)
#pragma unroll
        for (int ni = 0; ni < 2; ni++)
          acc[mi][ni] = __builtin_amdgcn_mfma_f32_16x16x32_bf16(af[mi], bfr[ni], acc[mi][ni], 0, 0, 0);
    }
    barf();                                       // all waves done reading buf `cur`
  }

  // epilogue: C/D layout col=lane&15, row=quad*4+reg
#pragma unroll
  for (int mi = 0; mi < 4; mi++) {
#pragma unroll
    for (int ni = 0; ni < 2; ni++) {
      int col = bn * 64 + wc * 32 + ni * 16 + lr;
      float bv = bias[col];
#pragma unroll
      for (int rg = 0; rg < 4; ++rg) {
        int row = bm * 128 + wr * 64 + mi * 16 + quad * 4 + rg;
        out[(size_t)row * DOUT + col] = acc[mi][ni][rg] + bv;
      }
    }
  }
}

extern "C" void kernel_launch(void* const* d_in, const int* in_sizes, int n_in,
                              void* d_out, int out_size, void* d_ws, size_t ws_size,
                              hipStream_t stream) {
  const float* x    = (const float*)d_in[0];
  const float* phi  = (const float*)d_in[1];
  const float* la   = (const float*)d_in[2];
  const float* lb   = (const float*)d_in[3];
  const float* W    = (const float*)d_in[4];
  const float* bias = (const float*)d_in[5];
  const int*   inst = (const int*)d_in[6];
  const int*   pad  = (const int*)d_in[7];
  float* out = (float*)d_out;

  char* ws = (char*)d_ws;
  unsigned short* xb  = (unsigned short*)ws;                   // 8388608 B
  unsigned short* Wc  = (unsigned short*)(ws + 8388608);       // 1072*1024*2 = 2195456 B
  unsigned short* B2T = (unsigned short*)(ws + 10584064);      // [1024][32] bf16 = 65536 B
  float* mwzP = (float*)(ws + 10649600);                       // [4][40][4096] f32 = 2621440 B
  unsigned short* gb  = (unsigned short*)(ws + 13271040);      // [4096][32] bf16 = 262144 B
  int*   thr  = (int*)(ws + 13533184);                         // 16 B

  hipLaunchKernelGGL(k_prep,      dim3(321),    dim3(256),  0, stream,
                     phi, la, lb, inst, Wc, B2T, thr);
  hipLaunchKernelGGL(k_mwz,       dim3(8448),   dim3(256),  0, stream,
                     x, (const float4*)x, (ushort4*)xb, Wc, W, Wc, mwzP);
  hipLaunchKernelGGL(k_scan_gate, dim3(4, 32),  dim3(1024), 0, stream, mwzP, pad, thr, gb);
  hipLaunchKernelGGL(k_gemm,      dim3(512),    dim3(256),  0, stream, xb, Wc, gb, B2T, out, bias);
}